// Round 9
// baseline (304.746 us; speedup 1.0000x reference)
//
#include <hip/hip_runtime.h>

#define ALPHA 0.2f
#define LDA 136   // epilogue LDS row stride in shorts (272 B)

typedef short bf16x8 __attribute__((ext_vector_type(8)));
typedef float f32x4  __attribute__((ext_vector_type(4)));

static __device__ __forceinline__ float bf2f(unsigned short u) {
    union { unsigned int i; float f; } v; v.i = ((unsigned int)u) << 16; return v.f;
}
static __device__ __forceinline__ unsigned short f2bf(float f) {
    union { float f; unsigned int i; } v; v.f = f;
    unsigned int x = v.i;
    return (unsigned short)((x + 0x7fffu + ((x >> 16) & 1u)) >> 16);  // RNE
}

// wT[c][k] = bf16(w[k][c]).  32 blocks x 128 thr: block b does k-slice
// [(b&15)*8, +8) of matrix b>>4; thread c reads 8 coalesced fp32, writes 16 B.
__global__ __launch_bounds__(128)
void prep_wT_kernel(const float* __restrict__ w1, const float* __restrict__ w2,
                    unsigned short* __restrict__ wT1, unsigned short* __restrict__ wT2)
{
    const int b = blockIdx.x;
    const float* w = (b >> 4) ? w2 : w1;
    unsigned short* wT = (b >> 4) ? wT2 : wT1;
    const int k0 = (b & 15) * 8;
    const int c = threadIdx.x;          // 0..127

    ushort4 u0, u1;
    u0.x = f2bf(w[(k0 + 0) * 128 + c]); u0.y = f2bf(w[(k0 + 1) * 128 + c]);
    u0.z = f2bf(w[(k0 + 2) * 128 + c]); u0.w = f2bf(w[(k0 + 3) * 128 + c]);
    u1.x = f2bf(w[(k0 + 4) * 128 + c]); u1.y = f2bf(w[(k0 + 5) * 128 + c]);
    u1.z = f2bf(w[(k0 + 6) * 128 + c]); u1.w = f2bf(w[(k0 + 7) * 128 + c]);
    *(ushort4*)&wT[c * 128 + k0]     = u0;
    *(ushort4*)&wT[c * 128 + k0 + 4] = u1;
}

// Staging-free MFMA GEMM + fused score dots.
// A and B fragments load DIRECTLY from global (no LDS staging, no K-loop
// barriers): A lane(m,q) <- src[row m][ks*32+q*8..+8]; B <- wT row t*16+m,
// same offsets (wT is 32 KB, L2-hot). LDS only for the coalescing epilogue.
template <bool SRC_BF>
__global__ __launch_bounds__(256)
void gemm_score_mfma(const void* __restrict__ srcv,
                     const unsigned short* __restrict__ wT,   // [c][k] bf16
                     const float* __restrict__ a_in,
                     const float* __restrict__ a_out,
                     unsigned short* __restrict__ hid,
                     float* __restrict__ s_in,
                     float* __restrict__ s_out,
                     int n)
{
    __shared__ short Es[64 * LDA];    // 17408 B, epilogue staging
    __shared__ float aS[2][128];      // 1 KB

    const int tid  = threadIdx.x;
    const int lane = tid & 63;
    const int wv   = tid >> 6;
    const int m    = lane & 15;
    const int q    = lane >> 4;
    const int rbase = blockIdx.x * 64;
    const int row   = rbase + wv * 16 + m;     // this lane's A row
    const bool rok  = (row < n);

    if (tid < 128) { aS[0][tid] = a_in[tid]; aS[1][tid] = a_out[tid]; }
    __syncthreads();

    // A fragments for the 4 k-chunks
    bf16x8 aF[4];
    if (SRC_BF) {
        const unsigned short* src = (const unsigned short*)srcv;
        const unsigned short* p = &src[(size_t)row * 128 + q * 8];
        #pragma unroll
        for (int ks = 0; ks < 4; ks++)
            aF[ks] = rok ? *(const bf16x8*)(p + ks * 32) : (bf16x8){0,0,0,0,0,0,0,0};
    } else {
        const float* src = (const float*)srcv;
        const float* p = &src[(size_t)row * 128 + q * 8];
        #pragma unroll
        for (int ks = 0; ks < 4; ks++) {
            if (rok) {
                float4 v0 = *(const float4*)(p + ks * 32);
                float4 v1 = *(const float4*)(p + ks * 32 + 4);
                bf16x8 a;
                a[0] = (short)f2bf(v0.x); a[1] = (short)f2bf(v0.y);
                a[2] = (short)f2bf(v0.z); a[3] = (short)f2bf(v0.w);
                a[4] = (short)f2bf(v1.x); a[5] = (short)f2bf(v1.y);
                a[6] = (short)f2bf(v1.z); a[7] = (short)f2bf(v1.w);
                aF[ks] = a;
            } else aF[ks] = (bf16x8){0,0,0,0,0,0,0,0};
        }
    }

    f32x4 acc[8];
    #pragma unroll
    for (int t = 0; t < 8; t++) acc[t] = (f32x4){0.f, 0.f, 0.f, 0.f};

    const unsigned short* Bp = &wT[m * 128 + q * 8];   // row m, +t*16 rows
    #pragma unroll
    for (int t = 0; t < 8; t++) {
        #pragma unroll
        for (int ks = 0; ks < 4; ks++) {
            bf16x8 bF = *(const bf16x8*)(Bp + ((size_t)t * 16 * 128) + ks * 32);
            acc[t] = __builtin_amdgcn_mfma_f32_16x16x32_bf16(aF[ks], bF, acc[t], 0, 0, 0);
        }
    }

    // fused score dots from fp32 accumulators
    float pin[4] = {0.f, 0.f, 0.f, 0.f}, pout[4] = {0.f, 0.f, 0.f, 0.f};
    #pragma unroll
    for (int t = 0; t < 8; t++) {
        float ai = aS[0][t * 16 + m];
        float ao = aS[1][t * 16 + m];
        #pragma unroll
        for (int r = 0; r < 4; r++) {
            pin[r]  += acc[t][r] * ai;
            pout[r] += acc[t][r] * ao;
        }
    }
    #pragma unroll
    for (int msk = 8; msk >= 1; msk >>= 1) {
        #pragma unroll
        for (int r = 0; r < 4; r++) {
            pin[r]  += __shfl_xor(pin[r],  msk);
            pout[r] += __shfl_xor(pout[r], msk);
        }
    }
    if (m == 0) {
        #pragma unroll
        for (int r = 0; r < 4; r++) {
            int g = rbase + wv * 16 + q * 4 + r;
            if (g < n) { s_in[g] = pin[r]; s_out[g] = pout[r]; }
        }
    }

    // epilogue: acc -> Es (bf16) -> coalesced 16 B global stores
    // C layout: row = q*4 + r, col = t*16 + m (within wave's 16-row strip)
    #pragma unroll
    for (int t = 0; t < 8; t++)
        #pragma unroll
        for (int r = 0; r < 4; r++)
            Es[(wv * 16 + q * 4 + r) * LDA + t * 16 + m] = (short)f2bf(acc[t][r]);
    __syncthreads();
    #pragma unroll
    for (int i = 0; i < 4; i++) {
        int e = tid + i * 256;
        int r = e >> 4, j = (e & 15) * 8;
        int gr = rbase + r;
        if (gr < n) {
            int4 v = *(const int4*)&Es[r * LDA + j];
            *(int4*)&hid[(size_t)gr * 128 + j] = v;
        }
    }
}

// Fused aggregate (unchanged from round 8): one wave per node.
// lanes 0-15: softmax via 16-lane shuffles; all lanes: 4 x 1KB gathers.
template <bool FINAL>
__global__ __launch_bounds__(256)
void gat_aggregate_kernel(const unsigned short* __restrict__ hid,
                          const float* __restrict__ s_in,
                          const float* __restrict__ s_out,
                          const int* __restrict__ dst,
                          const float* __restrict__ adj,
                          const float* __restrict__ bias,
                          void* __restrict__ outv,
                          int n)
{
    const int lane = threadIdx.x & 63;
    const int node = (blockIdx.x * 256 + threadIdx.x) >> 6;
    if (node >= n) return;

    float sc = -1e30f;
    int dk = 0;
    float av = 0.f;
    if (lane < 16) {
        int ei = node * 16 + lane;
        dk = dst[ei];
        av = adj[ei];
        float e = s_in[node] + s_out[dk];
        sc = (e > 0.f) ? e : ALPHA * e;            // LeakyReLU(0.2)
    }
    float m = sc;
    #pragma unroll
    for (int msk = 8; msk >= 1; msk >>= 1) m = fmaxf(m, __shfl_xor(m, msk));
    float p = (lane < 16) ? __expf(sc - m) : 0.f;
    float s = p;
    #pragma unroll
    for (int msk = 8; msk >= 1; msk >>= 1) s += __shfl_xor(s, msk);
    float wk = (lane < 16) ? av * p / s : 0.f;     // adj * softmax

    const int sub = lane >> 4;
    const int oct = lane & 15;
    int   gdk[4];
    float gwk[4];
    #pragma unroll
    for (int j = 0; j < 4; j++) {
        gdk[j] = __shfl(dk, 4 * j + sub);
        gwk[j] = __shfl(wk, 4 * j + sub);
    }

    float acc[8];
    #pragma unroll
    for (int i = 0; i < 8; i++) acc[i] = 0.f;
    #pragma unroll
    for (int j = 0; j < 4; j++) {
        bf16x8 hv = *(const bf16x8*)&hid[(size_t)gdk[j] * 128 + oct * 8];
        float wj = gwk[j];
        #pragma unroll
        for (int i = 0; i < 8; i++)
            acc[i] += wj * bf2f((unsigned short)hv[i]);
    }
    #pragma unroll
    for (int i = 0; i < 8; i++) {
        acc[i] += __shfl_xor(acc[i], 16);
        acc[i] += __shfl_xor(acc[i], 32);
    }

    if (lane < 16) {
        float4 b0 = *(const float4*)&bias[oct * 8];
        float4 b1 = *(const float4*)&bias[oct * 8 + 4];
        float o[8];
        o[0] = fmaxf(acc[0] + b0.x, 0.f); o[1] = fmaxf(acc[1] + b0.y, 0.f);
        o[2] = fmaxf(acc[2] + b0.z, 0.f); o[3] = fmaxf(acc[3] + b0.w, 0.f);
        o[4] = fmaxf(acc[4] + b1.x, 0.f); o[5] = fmaxf(acc[5] + b1.y, 0.f);
        o[6] = fmaxf(acc[6] + b1.z, 0.f); o[7] = fmaxf(acc[7] + b1.w, 0.f);

        const size_t obase = (size_t)node * 128 + oct * 8;
        if (FINAL) {
            float* of = (float*)outv;
            *(float4*)&of[obase]     = make_float4(o[0], o[1], o[2], o[3]);
            *(float4*)&of[obase + 4] = make_float4(o[4], o[5], o[6], o[7]);
        } else {
            unsigned short* oh = (unsigned short*)outv;
            ushort4 u0, u1;
            u0.x = f2bf(o[0]); u0.y = f2bf(o[1]); u0.z = f2bf(o[2]); u0.w = f2bf(o[3]);
            u1.x = f2bf(o[4]); u1.y = f2bf(o[5]); u1.z = f2bf(o[6]); u1.w = f2bf(o[7]);
            *(ushort4*)&oh[obase]     = u0;
            *(ushort4*)&oh[obase + 4] = u1;
        }
    }
}

extern "C" void kernel_launch(void* const* d_in, const int* in_sizes, int n_in,
                              void* d_out, int out_size, void* d_ws, size_t ws_size,
                              hipStream_t stream)
{
    const float* x      = (const float*)d_in[0];
    const int*   dst    = (const int*)d_in[1];
    const float* adj    = (const float*)d_in[2];
    const float* w1     = (const float*)d_in[3];
    const float* a_in1  = (const float*)d_in[4];
    const float* a_out1 = (const float*)d_in[5];
    const float* b1     = (const float*)d_in[6];
    const float* w2     = (const float*)d_in[7];
    const float* a_in2  = (const float*)d_in[8];
    const float* a_out2 = (const float*)d_in[9];
    const float* b2     = (const float*)d_in[10];

    const int N = in_sizes[0] / 128;               // 100000

    // ws: hid bf16 (25.6MB) | s_in | s_out | wT1 | wT2
    unsigned short* hid   = (unsigned short*)d_ws;
    float*          s_in  = (float*)(hid + (size_t)N * 128);
    float*          s_out = s_in + N;
    unsigned short* wT1   = (unsigned short*)(s_out + N);
    unsigned short* wT2   = wT1 + 128 * 128;
    // layer-1 activation h1 (bf16) lives in the upper half of the fp32 d_out
    unsigned short* h1    = (unsigned short*)d_out + out_size;

    dim3 blk(256);
    dim3 ggrid((N + 63) / 64);                     // 1563
    dim3 agrid((N + 3) / 4);                       // 25000 (1 node/wave)

    prep_wT_kernel<<<32, 128, 0, stream>>>(w1, w2, wT1, wT2);

    // Layer 1
    gemm_score_mfma<false><<<ggrid, blk, 0, stream>>>(x,  wT1, a_in1, a_out1,
                                                      hid, s_in, s_out, N);
    gat_aggregate_kernel<false><<<agrid, blk, 0, stream>>>(hid, s_in, s_out, dst,
                                                           adj, b1, h1, N);
    // Layer 2
    gemm_score_mfma<true><<<ggrid, blk, 0, stream>>>(h1, wT2, a_in2, a_out2,
                                                     hid, s_in, s_out, N);
    gat_aggregate_kernel<true><<<agrid, blk, 0, stream>>>(hid, s_in, s_out, dst,
                                                          adj, b2, d_out, N);
}

// Round 10
// 259.315 us; speedup vs baseline: 1.1752x; 1.1752x over previous
//
#include <hip/hip_runtime.h>

#define ALPHA 0.2f
#define LDA 136   // LDS row stride in shorts (272 B: aligned, conflict-balanced)

typedef short bf16x8 __attribute__((ext_vector_type(8)));
typedef float f32x4  __attribute__((ext_vector_type(4)));

static __device__ __forceinline__ float bf2f(unsigned short u) {
    union { unsigned int i; float f; } v; v.i = ((unsigned int)u) << 16; return v.f;
}
static __device__ __forceinline__ unsigned short f2bf(float f) {
    union { float f; unsigned int i; } v; v.f = f;
    unsigned int x = v.i;
    return (unsigned short)((x + 0x7fffu + ((x >> 16) & 1u)) >> 16);  // RNE
}

// wT[c][k] = bf16(w[k][c]).  32 blocks x 128 thr (parallel, ~2 us).
__global__ __launch_bounds__(128)
void prep_wT_kernel(const float* __restrict__ w1, const float* __restrict__ w2,
                    unsigned short* __restrict__ wT1, unsigned short* __restrict__ wT2)
{
    const int b = blockIdx.x;
    const float* w = (b >> 4) ? w2 : w1;
    unsigned short* wT = (b >> 4) ? wT2 : wT1;
    const int k0 = (b & 15) * 8;
    const int c = threadIdx.x;          // 0..127

    ushort4 u0, u1;
    u0.x = f2bf(w[(k0 + 0) * 128 + c]); u0.y = f2bf(w[(k0 + 1) * 128 + c]);
    u0.z = f2bf(w[(k0 + 2) * 128 + c]); u0.w = f2bf(w[(k0 + 3) * 128 + c]);
    u1.x = f2bf(w[(k0 + 4) * 128 + c]); u1.y = f2bf(w[(k0 + 5) * 128 + c]);
    u1.z = f2bf(w[(k0 + 6) * 128 + c]); u1.w = f2bf(w[(k0 + 7) * 128 + c]);
    *(ushort4*)&wT[c * 128 + k0]     = u0;
    *(ushort4*)&wT[c * 128 + k0 + 4] = u1;
}

// MFMA GEMM + fused score dots.
// B (wT) staged in LDS ONCE per block (the r8-vs-r9 A/B showed per-wave global
// B re-reads regress); A fragments load directly from global, issued before
// the staging loop so they overlap it. Epilogue tile ALIASES Bs after a
// barrier: LDS 35 KB -> 4 blocks/CU.
template <bool SRC_BF>
__global__ __launch_bounds__(256, 4)
void gemm_score_mfma(const void* __restrict__ srcv,
                     const unsigned short* __restrict__ wT,   // [c][k] bf16
                     const float* __restrict__ a_in,
                     const float* __restrict__ a_out,
                     unsigned short* __restrict__ hid,
                     float* __restrict__ s_in,
                     float* __restrict__ s_out,
                     int n)
{
    __shared__ short Bs[128 * LDA];   // 34816 B (epilogue reuses first half)
    __shared__ float aS[2][128];      // 1 KB

    const int tid  = threadIdx.x;
    const int lane = tid & 63;
    const int wv   = tid >> 6;
    const int m    = lane & 15;
    const int q    = lane >> 4;
    const int rbase = blockIdx.x * 64;
    const int row   = rbase + wv * 16 + m;
    const bool rok  = (row < n);

    if (tid < 128) { aS[0][tid] = a_in[tid]; aS[1][tid] = a_out[tid]; }

    // A fragments direct from global (independent loads, overlap B staging)
    bf16x8 aF[4];
    if (SRC_BF) {
        const unsigned short* src = (const unsigned short*)srcv;
        const unsigned short* p = &src[(size_t)row * 128 + q * 8];
        #pragma unroll
        for (int ks = 0; ks < 4; ks++)
            aF[ks] = rok ? *(const bf16x8*)(p + ks * 32) : (bf16x8){0,0,0,0,0,0,0,0};
    } else {
        const float* src = (const float*)srcv;
        const float* p = &src[(size_t)row * 128 + q * 8];
        #pragma unroll
        for (int ks = 0; ks < 4; ks++) {
            if (rok) {
                float4 v0 = *(const float4*)(p + ks * 32);
                float4 v1 = *(const float4*)(p + ks * 32 + 4);
                bf16x8 a;
                a[0] = (short)f2bf(v0.x); a[1] = (short)f2bf(v0.y);
                a[2] = (short)f2bf(v0.z); a[3] = (short)f2bf(v0.w);
                a[4] = (short)f2bf(v1.x); a[5] = (short)f2bf(v1.y);
                a[6] = (short)f2bf(v1.z); a[7] = (short)f2bf(v1.w);
                aF[ks] = a;
            } else aF[ks] = (bf16x8){0,0,0,0,0,0,0,0};
        }
    }

    // stage B: wT (L2-hot 32 KB) -> Bs, 16 B copies
    #pragma unroll
    for (int i = 0; i < 8; i++) {
        int e = tid + i * 256;                // 2048 int4 units
        int nr = e >> 4, j = (e & 15) * 8;
        int4 v = *(const int4*)&wT[nr * 128 + j];
        *(int4*)&Bs[nr * LDA + j] = v;
    }
    __syncthreads();

    f32x4 acc[8];
    #pragma unroll
    for (int t = 0; t < 8; t++) acc[t] = (f32x4){0.f, 0.f, 0.f, 0.f};

    const short* Bbase = &Bs[m * LDA + q * 8];
    #pragma unroll
    for (int ks = 0; ks < 4; ks++) {
        #pragma unroll
        for (int t = 0; t < 8; t++) {
            bf16x8 bF = *(const bf16x8*)(Bbase + t * 16 * LDA + ks * 32);
            acc[t] = __builtin_amdgcn_mfma_f32_16x16x32_bf16(aF[ks], bF, acc[t], 0, 0, 0);
        }
    }

    // fused score dots from fp32 accumulators
    float pin[4] = {0.f, 0.f, 0.f, 0.f}, pout[4] = {0.f, 0.f, 0.f, 0.f};
    #pragma unroll
    for (int t = 0; t < 8; t++) {
        float ai = aS[0][t * 16 + m];
        float ao = aS[1][t * 16 + m];
        #pragma unroll
        for (int r = 0; r < 4; r++) {
            pin[r]  += acc[t][r] * ai;
            pout[r] += acc[t][r] * ao;
        }
    }
    #pragma unroll
    for (int msk = 8; msk >= 1; msk >>= 1) {
        #pragma unroll
        for (int r = 0; r < 4; r++) {
            pin[r]  += __shfl_xor(pin[r],  msk);
            pout[r] += __shfl_xor(pout[r], msk);
        }
    }
    if (m == 0) {
        #pragma unroll
        for (int r = 0; r < 4; r++) {
            int g = rbase + wv * 16 + q * 4 + r;
            if (g < n) { s_in[g] = pin[r]; s_out[g] = pout[r]; }
        }
    }

    // epilogue: alias Es onto Bs (all Bs reads are done)
    __syncthreads();
    short* Es = Bs;
    #pragma unroll
    for (int t = 0; t < 8; t++)
        #pragma unroll
        for (int r = 0; r < 4; r++)
            Es[(wv * 16 + q * 4 + r) * LDA + t * 16 + m] = (short)f2bf(acc[t][r]);
    __syncthreads();
    #pragma unroll
    for (int i = 0; i < 4; i++) {
        int e = tid + i * 256;
        int r = e >> 4, j = (e & 15) * 8;
        int gr = rbase + r;
        if (gr < n) {
            int4 v = *(const int4*)&Es[r * LDA + j];
            *(int4*)&hid[(size_t)gr * 128 + j] = v;
        }
    }
}

// Fused aggregate: one wave per node.
// lanes 0-15: softmax via 16-lane shuffles (8 shfl total);
// gather: r7's fastest pattern (lane owns 2 cols, 16 x 256B row reads) with
// dk/wk broadcast via v_readlane (SALU) instead of 32 ds_bpermute shuffles.
template <bool FINAL>
__global__ __launch_bounds__(256)
void gat_aggregate_kernel(const unsigned short* __restrict__ hid,
                          const float* __restrict__ s_in,
                          const float* __restrict__ s_out,
                          const int* __restrict__ dst,
                          const float* __restrict__ adj,
                          const float* __restrict__ bias,
                          void* __restrict__ outv,
                          int n)
{
    const int lane = threadIdx.x & 63;
    const int node = (blockIdx.x * 256 + threadIdx.x) >> 6;
    if (node >= n) return;

    float sc = -1e30f;
    int dk = 0;
    float av = 0.f;
    if (lane < 16) {
        int ei = node * 16 + lane;
        dk = dst[ei];
        av = adj[ei];
        float e = s_in[node] + s_out[dk];
        sc = (e > 0.f) ? e : ALPHA * e;            // LeakyReLU(0.2)
    }
    float m = sc;
    #pragma unroll
    for (int msk = 8; msk >= 1; msk >>= 1) m = fmaxf(m, __shfl_xor(m, msk));
    float p = (lane < 16) ? __expf(sc - m) : 0.f;
    float s = p;
    #pragma unroll
    for (int msk = 8; msk >= 1; msk >>= 1) s += __shfl_xor(s, msk);
    float wk = (lane < 16) ? av * p / s : 0.f;     // adj * softmax

    // gather: lane owns cols 2*lane, 2*lane+1; dk/wk via readlane (SGPR)
    const int c = lane * 2;
    float accx = 0.f, accy = 0.f;
    #pragma unroll
    for (int k = 0; k < 16; k++) {
        int   sdk = __builtin_amdgcn_readlane(dk, k);
        float swk = __int_as_float(__builtin_amdgcn_readlane(__float_as_int(wk), k));
        ushort2 hq = *(const ushort2*)&hid[(size_t)sdk * 128 + c];
        accx += swk * bf2f(hq.x);
        accy += swk * bf2f(hq.y);
    }
    float ox = fmaxf(accx + bias[c],     0.f);
    float oy = fmaxf(accy + bias[c + 1], 0.f);

    const size_t oidx = (size_t)node * 128 + c;
    if (FINAL) {
        *(float2*)&((float*)outv)[oidx] = make_float2(ox, oy);
    } else {
        ushort2 ov; ov.x = f2bf(ox); ov.y = f2bf(oy);
        *(ushort2*)&((unsigned short*)outv)[oidx] = ov;
    }
}

extern "C" void kernel_launch(void* const* d_in, const int* in_sizes, int n_in,
                              void* d_out, int out_size, void* d_ws, size_t ws_size,
                              hipStream_t stream)
{
    const float* x      = (const float*)d_in[0];
    const int*   dst    = (const int*)d_in[1];
    const float* adj    = (const float*)d_in[2];
    const float* w1     = (const float*)d_in[3];
    const float* a_in1  = (const float*)d_in[4];
    const float* a_out1 = (const float*)d_in[5];
    const float* b1     = (const float*)d_in[6];
    const float* w2     = (const float*)d_in[7];
    const float* a_in2  = (const float*)d_in[8];
    const float* a_out2 = (const float*)d_in[9];
    const float* b2     = (const float*)d_in[10];

    const int N = in_sizes[0] / 128;               // 100000

    // ws: hid bf16 (25.6MB) | s_in | s_out | wT1 | wT2
    unsigned short* hid   = (unsigned short*)d_ws;
    float*          s_in  = (float*)(hid + (size_t)N * 128);
    float*          s_out = s_in + N;
    unsigned short* wT1   = (unsigned short*)(s_out + N);
    unsigned short* wT2   = wT1 + 128 * 128;
    // layer-1 activation h1 (bf16) lives in the upper half of the fp32 d_out
    unsigned short* h1    = (unsigned short*)d_out + out_size;

    dim3 blk(256);
    dim3 ggrid((N + 63) / 64);                     // 1563
    dim3 agrid((N + 3) / 4);                       // 25000 (1 node/wave)

    prep_wT_kernel<<<32, 128, 0, stream>>>(w1, w2, wT1, wT2);

    // Layer 1
    gemm_score_mfma<false><<<ggrid, blk, 0, stream>>>(x,  wT1, a_in1, a_out1,
                                                      hid, s_in, s_out, N);
    gat_aggregate_kernel<false><<<agrid, blk, 0, stream>>>(hid, s_in, s_out, dst,
                                                           adj, b1, h1, N);
    // Layer 2
    gemm_score_mfma<true><<<ggrid, blk, 0, stream>>>(h1, wT2, a_in2, a_out2,
                                                     hid, s_in, s_out, N);
    gat_aggregate_kernel<true><<<agrid, blk, 0, stream>>>(hid, s_in, s_out, dst,
                                                          adj, b2, d_out, N);
}

// Round 11
// 256.725 us; speedup vs baseline: 1.1871x; 1.0101x over previous
//
#include <hip/hip_runtime.h>

#define ALPHA 0.2f
#define LDA 136   // LDS row stride in shorts (272 B: aligned, conflict-balanced)

typedef short bf16x8 __attribute__((ext_vector_type(8)));
typedef float f32x4  __attribute__((ext_vector_type(4)));

static __device__ __forceinline__ float bf2f(unsigned short u) {
    union { unsigned int i; float f; } v; v.i = ((unsigned int)u) << 16; return v.f;
}
static __device__ __forceinline__ unsigned short f2bf(float f) {
    union { float f; unsigned int i; } v; v.f = f;
    unsigned int x = v.i;
    return (unsigned short)((x + 0x7fffu + ((x >> 16) & 1u)) >> 16);  // RNE
}

// wT[c][k] = bf16(w[k][c]).  32 blocks x 128 thr (parallel, ~2 us).
__global__ __launch_bounds__(128)
void prep_wT_kernel(const float* __restrict__ w1, const float* __restrict__ w2,
                    unsigned short* __restrict__ wT1, unsigned short* __restrict__ wT2)
{
    const int b = blockIdx.x;
    const float* w = (b >> 4) ? w2 : w1;
    unsigned short* wT = (b >> 4) ? wT2 : wT1;
    const int k0 = (b & 15) * 8;
    const int c = threadIdx.x;          // 0..127

    ushort4 u0, u1;
    u0.x = f2bf(w[(k0 + 0) * 128 + c]); u0.y = f2bf(w[(k0 + 1) * 128 + c]);
    u0.z = f2bf(w[(k0 + 2) * 128 + c]); u0.w = f2bf(w[(k0 + 3) * 128 + c]);
    u1.x = f2bf(w[(k0 + 4) * 128 + c]); u1.y = f2bf(w[(k0 + 5) * 128 + c]);
    u1.z = f2bf(w[(k0 + 6) * 128 + c]); u1.w = f2bf(w[(k0 + 7) * 128 + c]);
    *(ushort4*)&wT[c * 128 + k0]     = u0;
    *(ushort4*)&wT[c * 128 + k0 + 4] = u1;
}

// Layer-1 GEMM + fused score dots (r10 structure: B in LDS, A direct-global,
// epilogue aliases Bs).  Writes hid_L1 (bf16) + s_in1/s_out1.
__global__ __launch_bounds__(256, 4)
void gemm_score_mfma(const float* __restrict__ src,      // x, fp32
                     const unsigned short* __restrict__ wT,
                     const float* __restrict__ a_in,
                     const float* __restrict__ a_out,
                     unsigned short* __restrict__ hid,
                     float* __restrict__ s_in,
                     float* __restrict__ s_out,
                     int n)
{
    __shared__ short Bs[128 * LDA];   // 34816 B (epilogue reuses first half)
    __shared__ float aS[2][128];

    const int tid  = threadIdx.x;
    const int lane = tid & 63;
    const int wv   = tid >> 6;
    const int m    = lane & 15;
    const int q    = lane >> 4;
    const int rbase = blockIdx.x * 64;
    const int row   = rbase + wv * 16 + m;
    const bool rok  = (row < n);

    if (tid < 128) { aS[0][tid] = a_in[tid]; aS[1][tid] = a_out[tid]; }

    bf16x8 aF[4];
    {
        const float* p = &src[(size_t)row * 128 + q * 8];
        #pragma unroll
        for (int ks = 0; ks < 4; ks++) {
            if (rok) {
                float4 v0 = *(const float4*)(p + ks * 32);
                float4 v1 = *(const float4*)(p + ks * 32 + 4);
                bf16x8 a;
                a[0] = (short)f2bf(v0.x); a[1] = (short)f2bf(v0.y);
                a[2] = (short)f2bf(v0.z); a[3] = (short)f2bf(v0.w);
                a[4] = (short)f2bf(v1.x); a[5] = (short)f2bf(v1.y);
                a[6] = (short)f2bf(v1.z); a[7] = (short)f2bf(v1.w);
                aF[ks] = a;
            } else aF[ks] = (bf16x8){0,0,0,0,0,0,0,0};
        }
    }

    #pragma unroll
    for (int i = 0; i < 8; i++) {
        int e = tid + i * 256;
        int nr = e >> 4, j = (e & 15) * 8;
        int4 v = *(const int4*)&wT[nr * 128 + j];
        *(int4*)&Bs[nr * LDA + j] = v;
    }
    __syncthreads();

    f32x4 acc[8];
    #pragma unroll
    for (int t = 0; t < 8; t++) acc[t] = (f32x4){0.f, 0.f, 0.f, 0.f};

    const short* Bbase = &Bs[m * LDA + q * 8];
    #pragma unroll
    for (int ks = 0; ks < 4; ks++) {
        #pragma unroll
        for (int t = 0; t < 8; t++) {
            bf16x8 bF = *(const bf16x8*)(Bbase + t * 16 * LDA + ks * 32);
            acc[t] = __builtin_amdgcn_mfma_f32_16x16x32_bf16(aF[ks], bF, acc[t], 0, 0, 0);
        }
    }

    float pin[4] = {0.f, 0.f, 0.f, 0.f}, pout[4] = {0.f, 0.f, 0.f, 0.f};
    #pragma unroll
    for (int t = 0; t < 8; t++) {
        float ai = aS[0][t * 16 + m];
        float ao = aS[1][t * 16 + m];
        #pragma unroll
        for (int r = 0; r < 4; r++) {
            pin[r]  += acc[t][r] * ai;
            pout[r] += acc[t][r] * ao;
        }
    }
    #pragma unroll
    for (int msk = 8; msk >= 1; msk >>= 1) {
        #pragma unroll
        for (int r = 0; r < 4; r++) {
            pin[r]  += __shfl_xor(pin[r],  msk);
            pout[r] += __shfl_xor(pout[r], msk);
        }
    }
    if (m == 0) {
        #pragma unroll
        for (int r = 0; r < 4; r++) {
            int g = rbase + wv * 16 + q * 4 + r;
            if (g < n) { s_in[g] = pin[r]; s_out[g] = pout[r]; }
        }
    }

    __syncthreads();
    short* Es = Bs;
    #pragma unroll
    for (int t = 0; t < 8; t++)
        #pragma unroll
        for (int r = 0; r < 4; r++)
            Es[(wv * 16 + q * 4 + r) * LDA + t * 16 + m] = (short)f2bf(acc[t][r]);
    __syncthreads();
    #pragma unroll
    for (int i = 0; i < 4; i++) {
        int e = tid + i * 256;
        int r = e >> 4, j = (e & 15) * 8;
        int gr = rbase + r;
        if (gr < n) {
            int4 v = *(const int4*)&Es[r * LDA + j];
            *(int4*)&hid[(size_t)gr * 128 + j] = v;
        }
    }
}

// FUSED aggregate(layer1) + GEMM(layer2).  Block = 64 nodes.
// Phase A: wave wv aggregates nodes [wv*16, +16): 4 lanes/node softmax
// (coalesced dst/adj loads, shfl_xor 1&2), then per node 16 x 256B gathers
// (dk/wk via readlane); h1 row = relu(acc+b1) written bf16 into LDS As.
// Phase B: r10 GEMM from As x Bs(wT2) with fused layer-2 score dots;
// writes hid_L2 + s_in2/s_out2.  Saves the 51 MB h1 global round-trip.
__global__ __launch_bounds__(256)
void fused_agg_gemm(const unsigned short* __restrict__ hid1,
                    const float* __restrict__ s_in1,
                    const float* __restrict__ s_out1,
                    const int* __restrict__ dst,
                    const float* __restrict__ adj,
                    const float* __restrict__ bias1,
                    const unsigned short* __restrict__ wT2,
                    const float* __restrict__ a_in2,
                    const float* __restrict__ a_out2,
                    unsigned short* __restrict__ hid2,
                    float* __restrict__ s_in2,
                    float* __restrict__ s_out2,
                    int n)
{
    __shared__ short As[64 * LDA];    // 17408 B: h1 tile (epilogue aliases it)
    __shared__ short Bs[128 * LDA];   // 34816 B
    __shared__ float aS[2][128];

    const int tid  = threadIdx.x;
    const int lane = tid & 63;
    const int wv   = tid >> 6;
    const int rbase = blockIdx.x * 64;

    if (tid < 128) { aS[0][tid] = a_in2[tid]; aS[1][tid] = a_out2[tid]; }

    // stage Bs (wT2, L2-hot)
    #pragma unroll
    for (int i = 0; i < 8; i++) {
        int e = tid + i * 256;
        int nr = e >> 4, j = (e & 15) * 8;
        int4 v = *(const int4*)&wT2[nr * 128 + j];
        *(int4*)&Bs[nr * LDA + j] = v;
    }

    // ---- Phase A: aggregate 16 nodes per wave ----
    const int jn  = lane >> 2;               // node-local 0..15
    const int kq  = lane & 3;                // edge quartet
    const int node = rbase + wv * 16 + jn;
    const bool nok = (node < n);

    int4   dk4 = make_int4(0, 0, 0, 0);
    float4 av4 = make_float4(0.f, 0.f, 0.f, 0.f);
    float  si  = 0.f;
    if (nok) {
        dk4 = *(const int4*)&dst[node * 16 + kq * 4];
        av4 = *(const float4*)&adj[node * 16 + kq * 4];
        si  = s_in1[node];
    }
    float e0 = si + s_out1[dk4.x], e1 = si + s_out1[dk4.y];
    float e2 = si + s_out1[dk4.z], e3 = si + s_out1[dk4.w];
    e0 = (e0 > 0.f) ? e0 : ALPHA * e0;  e1 = (e1 > 0.f) ? e1 : ALPHA * e1;
    e2 = (e2 > 0.f) ? e2 : ALPHA * e2;  e3 = (e3 > 0.f) ? e3 : ALPHA * e3;
    float mx = fmaxf(fmaxf(e0, e1), fmaxf(e2, e3));
    mx = fmaxf(mx, __shfl_xor(mx, 1));
    mx = fmaxf(mx, __shfl_xor(mx, 2));       // max over the node's 4 lanes
    float p0 = __expf(e0 - mx), p1 = __expf(e1 - mx);
    float p2 = __expf(e2 - mx), p3 = __expf(e3 - mx);
    float sm = p0 + p1 + p2 + p3;
    sm += __shfl_xor(sm, 1);
    sm += __shfl_xor(sm, 2);
    const float inv = __frcp_rn(sm);
    float4 wk4 = make_float4(av4.x * p0 * inv, av4.y * p1 * inv,
                             av4.z * p2 * inv, av4.w * p3 * inv);

    const int c = lane * 2;                  // this lane's 2 columns
    const float2 bia = *(const float2*)&bias1[c];

    for (int j2 = 0; j2 < 16; j2++) {        // wave's nodes, sequential
        float accx = 0.f, accy = 0.f;
        #pragma unroll
        for (int k = 0; k < 16; k++) {
            const int srcl = j2 * 4 + (k >> 2);
            int   sdk, swki;
            if ((k & 3) == 0) { sdk = __builtin_amdgcn_readlane(dk4.x, srcl);
                                swki = __builtin_amdgcn_readlane(__float_as_int(wk4.x), srcl); }
            else if ((k & 3) == 1) { sdk = __builtin_amdgcn_readlane(dk4.y, srcl);
                                swki = __builtin_amdgcn_readlane(__float_as_int(wk4.y), srcl); }
            else if ((k & 3) == 2) { sdk = __builtin_amdgcn_readlane(dk4.z, srcl);
                                swki = __builtin_amdgcn_readlane(__float_as_int(wk4.z), srcl); }
            else             { sdk = __builtin_amdgcn_readlane(dk4.w, srcl);
                                swki = __builtin_amdgcn_readlane(__float_as_int(wk4.w), srcl); }
            float swk = __int_as_float(swki);
            ushort2 hq = *(const ushort2*)&hid1[(size_t)sdk * 128 + c];
            accx += swk * bf2f(hq.x);
            accy += swk * bf2f(hq.y);
        }
        float ox = fmaxf(accx + bia.x, 0.f);
        float oy = fmaxf(accy + bia.y, 0.f);
        ushort2 hv; hv.x = f2bf(ox); hv.y = f2bf(oy);
        *(ushort2*)&As[(wv * 16 + j2) * LDA + c] = hv;   // h1 tile in LDS
    }
    __syncthreads();

    // ---- Phase B: GEMM from As x Bs ----
    const int m = lane & 15;
    const int q = lane >> 4;

    f32x4 acc[8];
    #pragma unroll
    for (int t = 0; t < 8; t++) acc[t] = (f32x4){0.f, 0.f, 0.f, 0.f};

    const short* Abase = &As[(wv * 16 + m) * LDA + q * 8];
    const short* Bbase = &Bs[m * LDA + q * 8];
    #pragma unroll
    for (int ks = 0; ks < 4; ks++) {
        bf16x8 aF = *(const bf16x8*)(Abase + ks * 32);
        #pragma unroll
        for (int t = 0; t < 8; t++) {
            bf16x8 bF = *(const bf16x8*)(Bbase + t * 16 * LDA + ks * 32);
            acc[t] = __builtin_amdgcn_mfma_f32_16x16x32_bf16(aF, bF, acc[t], 0, 0, 0);
        }
    }

    float pin[4] = {0.f, 0.f, 0.f, 0.f}, pout[4] = {0.f, 0.f, 0.f, 0.f};
    #pragma unroll
    for (int t = 0; t < 8; t++) {
        float ai = aS[0][t * 16 + m];
        float ao = aS[1][t * 16 + m];
        #pragma unroll
        for (int r = 0; r < 4; r++) {
            pin[r]  += acc[t][r] * ai;
            pout[r] += acc[t][r] * ao;
        }
    }
    #pragma unroll
    for (int msk = 8; msk >= 1; msk >>= 1) {
        #pragma unroll
        for (int r = 0; r < 4; r++) {
            pin[r]  += __shfl_xor(pin[r],  msk);
            pout[r] += __shfl_xor(pout[r], msk);
        }
    }
    if (m == 0) {
        #pragma unroll
        for (int r = 0; r < 4; r++) {
            int g = rbase + wv * 16 + q * 4 + r;
            if (g < n) { s_in2[g] = pin[r]; s_out2[g] = pout[r]; }
        }
    }

    __syncthreads();
    short* Es = As;                          // As fully consumed
    #pragma unroll
    for (int t = 0; t < 8; t++)
        #pragma unroll
        for (int r = 0; r < 4; r++)
            Es[(wv * 16 + q * 4 + r) * LDA + t * 16 + m] = (short)f2bf(acc[t][r]);
    __syncthreads();
    #pragma unroll
    for (int i = 0; i < 4; i++) {
        int e = tid + i * 256;
        int r = e >> 4, j = (e & 15) * 8;
        int gr = rbase + r;
        if (gr < n) {
            int4 v = *(const int4*)&Es[r * LDA + j];
            *(int4*)&hid2[(size_t)gr * 128 + j] = v;
        }
    }
}

// Final aggregate (r10 form): one wave/node, softmax on lanes 0-15,
// readlane-driven 256 B gathers, fp32 output.
__global__ __launch_bounds__(256)
void gat_aggregate_final(const unsigned short* __restrict__ hid,
                         const float* __restrict__ s_in,
                         const float* __restrict__ s_out,
                         const int* __restrict__ dst,
                         const float* __restrict__ adj,
                         const float* __restrict__ bias,
                         float* __restrict__ out,
                         int n)
{
    const int lane = threadIdx.x & 63;
    const int node = (blockIdx.x * 256 + threadIdx.x) >> 6;
    if (node >= n) return;

    float sc = -1e30f;
    int dk = 0;
    float av = 0.f;
    if (lane < 16) {
        int ei = node * 16 + lane;
        dk = dst[ei];
        av = adj[ei];
        float e = s_in[node] + s_out[dk];
        sc = (e > 0.f) ? e : ALPHA * e;
    }
    float m = sc;
    #pragma unroll
    for (int msk = 8; msk >= 1; msk >>= 1) m = fmaxf(m, __shfl_xor(m, msk));
    float p = (lane < 16) ? __expf(sc - m) : 0.f;
    float s = p;
    #pragma unroll
    for (int msk = 8; msk >= 1; msk >>= 1) s += __shfl_xor(s, msk);
    float wk = (lane < 16) ? av * p / s : 0.f;

    const int c = lane * 2;
    float accx = 0.f, accy = 0.f;
    #pragma unroll
    for (int k = 0; k < 16; k++) {
        int   sdk = __builtin_amdgcn_readlane(dk, k);
        float swk = __int_as_float(__builtin_amdgcn_readlane(__float_as_int(wk), k));
        ushort2 hq = *(const ushort2*)&hid[(size_t)sdk * 128 + c];
        accx += swk * bf2f(hq.x);
        accy += swk * bf2f(hq.y);
    }
    float ox = fmaxf(accx + bias[c],     0.f);
    float oy = fmaxf(accy + bias[c + 1], 0.f);
    *(float2*)&out[(size_t)node * 128 + c] = make_float2(ox, oy);
}

extern "C" void kernel_launch(void* const* d_in, const int* in_sizes, int n_in,
                              void* d_out, int out_size, void* d_ws, size_t ws_size,
                              hipStream_t stream)
{
    const float* x      = (const float*)d_in[0];
    const int*   dst    = (const int*)d_in[1];
    const float* adj    = (const float*)d_in[2];
    const float* w1     = (const float*)d_in[3];
    const float* a_in1  = (const float*)d_in[4];
    const float* a_out1 = (const float*)d_in[5];
    const float* b1     = (const float*)d_in[6];
    const float* w2     = (const float*)d_in[7];
    const float* a_in2  = (const float*)d_in[8];
    const float* a_out2 = (const float*)d_in[9];
    const float* b2     = (const float*)d_in[10];

    const int N = in_sizes[0] / 128;               // 100000

    // ws: hid2 bf16 (25.6MB) | s_in1 | s_out1 | s_in2 | s_out2 | wT1 | wT2
    unsigned short* hid2  = (unsigned short*)d_ws;
    float*          s_in1 = (float*)(hid2 + (size_t)N * 128);
    float*          s_out1= s_in1 + N;
    float*          s_in2 = s_out1 + N;
    float*          s_out2= s_in2 + N;
    unsigned short* wT1   = (unsigned short*)(s_out2 + N);
    unsigned short* wT2   = wT1 + 128 * 128;
    // hid_L1 (bf16) lives in the upper half of the fp32 d_out (proven slot);
    // the final aggregate overwrites d_out only after hid_L1 is dead.
    unsigned short* hid1  = (unsigned short*)d_out + out_size;

    dim3 blk(256);
    dim3 ggrid((N + 63) / 64);                     // 1563
    dim3 agrid((N + 3) / 4);                       // 25000

    prep_wT_kernel<<<32, 128, 0, stream>>>(w1, w2, wT1, wT2);

    gemm_score_mfma<<<ggrid, blk, 0, stream>>>(x, wT1, a_in1, a_out1,
                                               hid1, s_in1, s_out1, N);
    fused_agg_gemm<<<ggrid, blk, 0, stream>>>(hid1, s_in1, s_out1, dst, adj, b1,
                                              wT2, a_in2, a_out2,
                                              hid2, s_in2, s_out2, N);
    gat_aggregate_final<<<agrid, blk, 0, stream>>>(hid2, s_in2, s_out2, dst, adj,
                                                   b2, (float*)d_out, N);
}

// Round 12
// 253.486 us; speedup vs baseline: 1.2022x; 1.0128x over previous
//
#include <hip/hip_runtime.h>

#define ALPHA 0.2f
#define LDA 136   // LDS row stride in shorts (272 B: aligned, conflict-balanced)

typedef short bf16x8 __attribute__((ext_vector_type(8)));
typedef float f32x4  __attribute__((ext_vector_type(4)));

static __device__ __forceinline__ float bf2f(unsigned short u) {
    union { unsigned int i; float f; } v; v.i = ((unsigned int)u) << 16; return v.f;
}
static __device__ __forceinline__ unsigned short f2bf(float f) {
    union { float f; unsigned int i; } v; v.f = f;
    unsigned int x = v.i;
    return (unsigned short)((x + 0x7fffu + ((x >> 16) & 1u)) >> 16);  // RNE
}

// wT[c][k] = bf16(w[k][c]).  32 blocks x 128 thr (parallel, ~2 us).
__global__ __launch_bounds__(128)
void prep_wT_kernel(const float* __restrict__ w1, const float* __restrict__ w2,
                    unsigned short* __restrict__ wT1, unsigned short* __restrict__ wT2)
{
    const int b = blockIdx.x;
    const float* w = (b >> 4) ? w2 : w1;
    unsigned short* wT = (b >> 4) ? wT2 : wT1;
    const int k0 = (b & 15) * 8;
    const int c = threadIdx.x;          // 0..127

    ushort4 u0, u1;
    u0.x = f2bf(w[(k0 + 0) * 128 + c]); u0.y = f2bf(w[(k0 + 1) * 128 + c]);
    u0.z = f2bf(w[(k0 + 2) * 128 + c]); u0.w = f2bf(w[(k0 + 3) * 128 + c]);
    u1.x = f2bf(w[(k0 + 4) * 128 + c]); u1.y = f2bf(w[(k0 + 5) * 128 + c]);
    u1.z = f2bf(w[(k0 + 6) * 128 + c]); u1.w = f2bf(w[(k0 + 7) * 128 + c]);
    *(ushort4*)&wT[c * 128 + k0]     = u0;
    *(ushort4*)&wT[c * 128 + k0 + 4] = u1;
}

// Layer-1 GEMM + fused score dots (r10 structure, unchanged: 27 us).
__global__ __launch_bounds__(256, 4)
void gemm_score_mfma(const float* __restrict__ src,      // x, fp32
                     const unsigned short* __restrict__ wT,
                     const float* __restrict__ a_in,
                     const float* __restrict__ a_out,
                     unsigned short* __restrict__ hid,
                     float* __restrict__ s_in,
                     float* __restrict__ s_out,
                     int n)
{
    __shared__ short Bs[128 * LDA];   // 34816 B (epilogue reuses first half)
    __shared__ float aS[2][128];

    const int tid  = threadIdx.x;
    const int lane = tid & 63;
    const int wv   = tid >> 6;
    const int m    = lane & 15;
    const int q    = lane >> 4;
    const int rbase = blockIdx.x * 64;
    const int row   = rbase + wv * 16 + m;
    const bool rok  = (row < n);

    if (tid < 128) { aS[0][tid] = a_in[tid]; aS[1][tid] = a_out[tid]; }

    bf16x8 aF[4];
    {
        const float* p = &src[(size_t)row * 128 + q * 8];
        #pragma unroll
        for (int ks = 0; ks < 4; ks++) {
            if (rok) {
                float4 v0 = *(const float4*)(p + ks * 32);
                float4 v1 = *(const float4*)(p + ks * 32 + 4);
                bf16x8 a;
                a[0] = (short)f2bf(v0.x); a[1] = (short)f2bf(v0.y);
                a[2] = (short)f2bf(v0.z); a[3] = (short)f2bf(v0.w);
                a[4] = (short)f2bf(v1.x); a[5] = (short)f2bf(v1.y);
                a[6] = (short)f2bf(v1.z); a[7] = (short)f2bf(v1.w);
                aF[ks] = a;
            } else aF[ks] = (bf16x8){0,0,0,0,0,0,0,0};
        }
    }

    #pragma unroll
    for (int i = 0; i < 8; i++) {
        int e = tid + i * 256;
        int nr = e >> 4, j = (e & 15) * 8;
        int4 v = *(const int4*)&wT[nr * 128 + j];
        *(int4*)&Bs[nr * LDA + j] = v;
    }
    __syncthreads();

    f32x4 acc[8];
    #pragma unroll
    for (int t = 0; t < 8; t++) acc[t] = (f32x4){0.f, 0.f, 0.f, 0.f};

    const short* Bbase = &Bs[m * LDA + q * 8];
    #pragma unroll
    for (int ks = 0; ks < 4; ks++) {
        #pragma unroll
        for (int t = 0; t < 8; t++) {
            bf16x8 bF = *(const bf16x8*)(Bbase + t * 16 * LDA + ks * 32);
            acc[t] = __builtin_amdgcn_mfma_f32_16x16x32_bf16(aF[ks], bF, acc[t], 0, 0, 0);
        }
    }

    float pin[4] = {0.f, 0.f, 0.f, 0.f}, pout[4] = {0.f, 0.f, 0.f, 0.f};
    #pragma unroll
    for (int t = 0; t < 8; t++) {
        float ai = aS[0][t * 16 + m];
        float ao = aS[1][t * 16 + m];
        #pragma unroll
        for (int r = 0; r < 4; r++) {
            pin[r]  += acc[t][r] * ai;
            pout[r] += acc[t][r] * ao;
        }
    }
    #pragma unroll
    for (int msk = 8; msk >= 1; msk >>= 1) {
        #pragma unroll
        for (int r = 0; r < 4; r++) {
            pin[r]  += __shfl_xor(pin[r],  msk);
            pout[r] += __shfl_xor(pout[r], msk);
        }
    }
    if (m == 0) {
        #pragma unroll
        for (int r = 0; r < 4; r++) {
            int g = rbase + wv * 16 + q * 4 + r;
            if (g < n) { s_in[g] = pin[r]; s_out[g] = pout[r]; }
        }
    }

    __syncthreads();
    short* Es = Bs;
    #pragma unroll
    for (int t = 0; t < 8; t++)
        #pragma unroll
        for (int r = 0; r < 4; r++)
            Es[(wv * 16 + q * 4 + r) * LDA + t * 16 + m] = (short)f2bf(acc[t][r]);
    __syncthreads();
    #pragma unroll
    for (int i = 0; i < 4; i++) {
        int e = tid + i * 256;
        int r = e >> 4, j = (e & 15) * 8;
        int gr = rbase + r;
        if (gr < n) {
            int4 v = *(const int4*)&Es[r * LDA + j];
            *(int4*)&hid[(size_t)gr * 128 + j] = v;
        }
    }
}

// FUSED aggregate(layer1) + GEMM(layer2), 2-pass B staging for occupancy.
// LDS: As 17.4 KB + Bs-half 17.4 KB + aS 1 KB = 35.8 KB -> 4 blocks/CU
// (was 53.2 KB -> 3): +33% waves for the latency-bound phase-A gather.
__global__ __launch_bounds__(256, 4)
void fused_agg_gemm(const unsigned short* __restrict__ hid1,
                    const float* __restrict__ s_in1,
                    const float* __restrict__ s_out1,
                    const int* __restrict__ dst,
                    const float* __restrict__ adj,
                    const float* __restrict__ bias1,
                    const unsigned short* __restrict__ wT2,
                    const float* __restrict__ a_in2,
                    const float* __restrict__ a_out2,
                    unsigned short* __restrict__ hid2,
                    float* __restrict__ s_in2,
                    float* __restrict__ s_out2,
                    int n)
{
    __shared__ short As[64 * LDA];    // h1 tile; epilogue aliases it
    __shared__ short Bs[64 * LDA];    // HALF of wT2 at a time
    __shared__ float aS[2][128];

    const int tid  = threadIdx.x;
    const int lane = tid & 63;
    const int wv   = tid >> 6;
    const int rbase = blockIdx.x * 64;

    if (tid < 128) { aS[0][tid] = a_in2[tid]; aS[1][tid] = a_out2[tid]; }

    // stage Bs pass 1: wT2 rows 0..63 (cols 0..63 of W2)
    #pragma unroll
    for (int i = 0; i < 4; i++) {
        int e = tid + i * 256;                // 1024 int4 units
        int nr = e >> 4, j = (e & 15) * 8;
        int4 v = *(const int4*)&wT2[nr * 128 + j];
        *(int4*)&Bs[nr * LDA + j] = v;
    }

    // ---- Phase A: aggregate 16 nodes per wave (4 lanes/node softmax) ----
    const int jn  = lane >> 2;
    const int kq  = lane & 3;
    const int node = rbase + wv * 16 + jn;
    const bool nok = (node < n);

    int4   dk4 = make_int4(0, 0, 0, 0);
    float4 av4 = make_float4(0.f, 0.f, 0.f, 0.f);
    float  si  = 0.f;
    if (nok) {
        dk4 = *(const int4*)&dst[node * 16 + kq * 4];
        av4 = *(const float4*)&adj[node * 16 + kq * 4];
        si  = s_in1[node];
    }
    float e0 = si + s_out1[dk4.x], e1 = si + s_out1[dk4.y];
    float e2 = si + s_out1[dk4.z], e3 = si + s_out1[dk4.w];
    e0 = (e0 > 0.f) ? e0 : ALPHA * e0;  e1 = (e1 > 0.f) ? e1 : ALPHA * e1;
    e2 = (e2 > 0.f) ? e2 : ALPHA * e2;  e3 = (e3 > 0.f) ? e3 : ALPHA * e3;
    float mx = fmaxf(fmaxf(e0, e1), fmaxf(e2, e3));
    mx = fmaxf(mx, __shfl_xor(mx, 1));
    mx = fmaxf(mx, __shfl_xor(mx, 2));
    float p0 = __expf(e0 - mx), p1 = __expf(e1 - mx);
    float p2 = __expf(e2 - mx), p3 = __expf(e3 - mx);
    float sm = p0 + p1 + p2 + p3;
    sm += __shfl_xor(sm, 1);
    sm += __shfl_xor(sm, 2);
    const float inv = __frcp_rn(sm);
    float4 wk4 = make_float4(av4.x * p0 * inv, av4.y * p1 * inv,
                             av4.z * p2 * inv, av4.w * p3 * inv);

    const int c = lane * 2;
    const float2 bia = *(const float2*)&bias1[c];

    for (int j2 = 0; j2 < 16; j2++) {
        float accx = 0.f, accy = 0.f;
        #pragma unroll
        for (int k = 0; k < 16; k++) {
            const int srcl = j2 * 4 + (k >> 2);
            int   sdk, swki;
            if ((k & 3) == 0) { sdk = __builtin_amdgcn_readlane(dk4.x, srcl);
                                swki = __builtin_amdgcn_readlane(__float_as_int(wk4.x), srcl); }
            else if ((k & 3) == 1) { sdk = __builtin_amdgcn_readlane(dk4.y, srcl);
                                swki = __builtin_amdgcn_readlane(__float_as_int(wk4.y), srcl); }
            else if ((k & 3) == 2) { sdk = __builtin_amdgcn_readlane(dk4.z, srcl);
                                swki = __builtin_amdgcn_readlane(__float_as_int(wk4.z), srcl); }
            else             { sdk = __builtin_amdgcn_readlane(dk4.w, srcl);
                                swki = __builtin_amdgcn_readlane(__float_as_int(wk4.w), srcl); }
            float swk = __int_as_float(swki);
            ushort2 hq = *(const ushort2*)&hid1[(size_t)sdk * 128 + c];
            accx += swk * bf2f(hq.x);
            accy += swk * bf2f(hq.y);
        }
        float ox = fmaxf(accx + bia.x, 0.f);
        float oy = fmaxf(accy + bia.y, 0.f);
        ushort2 hv; hv.x = f2bf(ox); hv.y = f2bf(oy);
        *(ushort2*)&As[(wv * 16 + j2) * LDA + c] = hv;
    }
    __syncthreads();

    // ---- Phase B: GEMM from As x Bs, two B passes ----
    const int m = lane & 15;
    const int q = lane >> 4;

    // hoist A-fragments so the epilogue can alias As
    bf16x8 aF[4];
    {
        const short* Abase = &As[(wv * 16 + m) * LDA + q * 8];
        #pragma unroll
        for (int ks = 0; ks < 4; ks++)
            aF[ks] = *(const bf16x8*)(Abase + ks * 32);
    }

    f32x4 acc[8];
    #pragma unroll
    for (int t = 0; t < 8; t++) acc[t] = (f32x4){0.f, 0.f, 0.f, 0.f};

    const short* Bbase = &Bs[m * LDA + q * 8];
    #pragma unroll
    for (int ks = 0; ks < 4; ks++) {
        #pragma unroll
        for (int t = 0; t < 4; t++) {       // pass 1: W cols 0..63
            bf16x8 bF = *(const bf16x8*)(Bbase + t * 16 * LDA + ks * 32);
            acc[t] = __builtin_amdgcn_mfma_f32_16x16x32_bf16(aF[ks], bF, acc[t], 0, 0, 0);
        }
    }
    __syncthreads();
    #pragma unroll
    for (int i = 0; i < 4; i++) {           // restage: wT2 rows 64..127
        int e = tid + i * 256;
        int nr = e >> 4, j = (e & 15) * 8;
        int4 v = *(const int4*)&wT2[(64 + nr) * 128 + j];
        *(int4*)&Bs[nr * LDA + j] = v;
    }
    __syncthreads();
    #pragma unroll
    for (int ks = 0; ks < 4; ks++) {
        #pragma unroll
        for (int t = 4; t < 8; t++) {       // pass 2: W cols 64..127
            bf16x8 bF = *(const bf16x8*)(Bbase + (t - 4) * 16 * LDA + ks * 32);
            acc[t] = __builtin_amdgcn_mfma_f32_16x16x32_bf16(aF[ks], bF, acc[t], 0, 0, 0);
        }
    }

    // fused layer-2 score dots
    float pin[4] = {0.f, 0.f, 0.f, 0.f}, pout[4] = {0.f, 0.f, 0.f, 0.f};
    #pragma unroll
    for (int t = 0; t < 8; t++) {
        float ai = aS[0][t * 16 + m];
        float ao = aS[1][t * 16 + m];
        #pragma unroll
        for (int r = 0; r < 4; r++) {
            pin[r]  += acc[t][r] * ai;
            pout[r] += acc[t][r] * ao;
        }
    }
    #pragma unroll
    for (int msk = 8; msk >= 1; msk >>= 1) {
        #pragma unroll
        for (int r = 0; r < 4; r++) {
            pin[r]  += __shfl_xor(pin[r],  msk);
            pout[r] += __shfl_xor(pout[r], msk);
        }
    }
    if (m == 0) {
        #pragma unroll
        for (int r = 0; r < 4; r++) {
            int g = rbase + wv * 16 + q * 4 + r;
            if (g < n) { s_in2[g] = pin[r]; s_out2[g] = pout[r]; }
        }
    }

    __syncthreads();
    short* Es = As;                          // aF hoisted: As dead
    #pragma unroll
    for (int t = 0; t < 8; t++)
        #pragma unroll
        for (int r = 0; r < 4; r++)
            Es[(wv * 16 + q * 4 + r) * LDA + t * 16 + m] = (short)f2bf(acc[t][r]);
    __syncthreads();
    #pragma unroll
    for (int i = 0; i < 4; i++) {
        int e = tid + i * 256;
        int r = e >> 4, j = (e & 15) * 8;
        int gr = rbase + r;
        if (gr < n) {
            int4 v = *(const int4*)&Es[r * LDA + j];
            *(int4*)&hid2[(size_t)gr * 128 + j] = v;
        }
    }
}

// Final aggregate (r10 form, unchanged): one wave/node, fp32 output.
__global__ __launch_bounds__(256)
void gat_aggregate_final(const unsigned short* __restrict__ hid,
                         const float* __restrict__ s_in,
                         const float* __restrict__ s_out,
                         const int* __restrict__ dst,
                         const float* __restrict__ adj,
                         const float* __restrict__ bias,
                         float* __restrict__ out,
                         int n)
{
    const int lane = threadIdx.x & 63;
    const int node = (blockIdx.x * 256 + threadIdx.x) >> 6;
    if (node >= n) return;

    float sc = -1e30f;
    int dk = 0;
    float av = 0.f;
    if (lane < 16) {
        int ei = node * 16 + lane;
        dk = dst[ei];
        av = adj[ei];
        float e = s_in[node] + s_out[dk];
        sc = (e > 0.f) ? e : ALPHA * e;
    }
    float m = sc;
    #pragma unroll
    for (int msk = 8; msk >= 1; msk >>= 1) m = fmaxf(m, __shfl_xor(m, msk));
    float p = (lane < 16) ? __expf(sc - m) : 0.f;
    float s = p;
    #pragma unroll
    for (int msk = 8; msk >= 1; msk >>= 1) s += __shfl_xor(s, msk);
    float wk = (lane < 16) ? av * p / s : 0.f;

    const int c = lane * 2;
    float accx = 0.f, accy = 0.f;
    #pragma unroll
    for (int k = 0; k < 16; k++) {
        int   sdk = __builtin_amdgcn_readlane(dk, k);
        float swk = __int_as_float(__builtin_amdgcn_readlane(__float_as_int(wk), k));
        ushort2 hq = *(const ushort2*)&hid[(size_t)sdk * 128 + c];
        accx += swk * bf2f(hq.x);
        accy += swk * bf2f(hq.y);
    }
    float ox = fmaxf(accx + bias[c],     0.f);
    float oy = fmaxf(accy + bias[c + 1], 0.f);
    *(float2*)&out[(size_t)node * 128 + c] = make_float2(ox, oy);
}

extern "C" void kernel_launch(void* const* d_in, const int* in_sizes, int n_in,
                              void* d_out, int out_size, void* d_ws, size_t ws_size,
                              hipStream_t stream)
{
    const float* x      = (const float*)d_in[0];
    const int*   dst    = (const int*)d_in[1];
    const float* adj    = (const float*)d_in[2];
    const float* w1     = (const float*)d_in[3];
    const float* a_in1  = (const float*)d_in[4];
    const float* a_out1 = (const float*)d_in[5];
    const float* b1     = (const float*)d_in[6];
    const float* w2     = (const float*)d_in[7];
    const float* a_in2  = (const float*)d_in[8];
    const float* a_out2 = (const float*)d_in[9];
    const float* b2     = (const float*)d_in[10];

    const int N = in_sizes[0] / 128;               // 100000

    // ws: hid2 bf16 (25.6MB) | s_in1 | s_out1 | s_in2 | s_out2 | wT1 | wT2
    unsigned short* hid2  = (unsigned short*)d_ws;
    float*          s_in1 = (float*)(hid2 + (size_t)N * 128);
    float*          s_out1= s_in1 + N;
    float*          s_in2 = s_out1 + N;
    float*          s_out2= s_in2 + N;
    unsigned short* wT1   = (unsigned short*)(s_out2 + N);
    unsigned short* wT2   = wT1 + 128 * 128;
    // hid_L1 (bf16) lives in the upper half of the fp32 d_out;
    // the final aggregate overwrites d_out only after hid_L1 is dead.
    unsigned short* hid1  = (unsigned short*)d_out + out_size;

    dim3 blk(256);
    dim3 ggrid((N + 63) / 64);                     // 1563
    dim3 agrid((N + 3) / 4);                       // 25000

    prep_wT_kernel<<<32, 128, 0, stream>>>(w1, w2, wT1, wT2);

    gemm_score_mfma<<<ggrid, blk, 0, stream>>>(x, wT1, a_in1, a_out1,
                                               hid1, s_in1, s_out1, N);
    fused_agg_gemm<<<ggrid, blk, 0, stream>>>(hid1, s_in1, s_out1, dst, adj, b1,
                                              wT2, a_in2, a_out2,
                                              hid2, s_in2, s_out2, N);
    gat_aggregate_final<<<agrid, blk, 0, stream>>>(hid2, s_in2, s_out2, dst, adj,
                                                   b2, (float*)d_out, N);
}